// Round 13
// baseline (57.213 us; speedup 1.0000x reference)
//
#include <hip/hip_runtime.h>

// Conv4d via implicit GEMM on MFMA (bf16 in, fp32 accum), SINGLE-PHASE.
// x (2,16,20^4) f32, w (16,32,3^4) f32 -> out (2,32,18^4) f32
//
// R13 = R12 with the global_load_lds staging fixed: LDS dest must be a
// WAVE-UNIFORM base (HW writes base + lane*16). R12 passed a per-lane
// address (l + t*8) -> compiler waterfall -> scattered writes -> holes ->
// MFMA read uninitialized LDS -> NaN. Restored R7/R11's verified pattern:
// l0 = l + (wv<<9) (uniform per wave), per-lane GLOBAL src, uniform tail.
//
// Structure (R12): stage ALL 9 slabs (115.2KB LDS, 1 block/CU), ONE
// barrier, then 81 uninterrupted (ab,c) compute steps the compiler can
// software-pipeline freely. af from L2-hot global wt. d-shift inner loop
// (9 B-reads -> 27 MFMA per ab). XCD swizzle. shfl+edgebuf epilogue
// (verified R4/R6/R7/R9/R10/R11). xt/wt prepass (R5/R7/R11).

typedef unsigned short ushort_t;
typedef __attribute__((ext_vector_type(8)))  __bf16 bf16x8;
typedef __attribute__((ext_vector_type(16))) float  f32x16;
typedef __attribute__((ext_vector_type(4)))  unsigned int uint4v;

__device__ __forceinline__ ushort_t f2bf(float f) {
    union { float f; unsigned int u; } v; v.f = f;
    unsigned int r = v.u + 0x7FFFu + ((v.u >> 16) & 1u);   // RNE
    return (ushort_t)(r >> 16);
}

__device__ __forceinline__ void gload16(const ushort_t* g, ushort_t* l) {
    __builtin_amdgcn_global_load_lds(
        (const __attribute__((address_space(1))) unsigned int*)g,
        (__attribute__((address_space(3))) unsigned int*)l, 16, 0, 0);
}

// ---------- fused prepass ----------
// blocks 0..1249: x (NCHW f32) -> xt (N,spatial,ic bf16)  [verified R5-R11]
// blocks 1250..1411: w (ic,oc,tap f32) -> wt [tap][oc][ic] bf16  [R9 layout]
__global__ __launch_bounds__(256) void prepass(const float* __restrict__ x,
                                               const float* __restrict__ w,
                                               ushort_t* __restrict__ xt,
                                               ushort_t* __restrict__ wt) {
    const int blk = blockIdx.x;
    if (blk < 1250) {
        const int g = blk * 256 + threadIdx.x;          // 0..319999
        const int n = g / 160000, rem = g % 160000;
        const float* xs = x + (size_t)n * 2560000 + rem;
        unsigned int pk[8];
        #pragma unroll
        for (int e = 0; e < 8; ++e) {
            unsigned int lo = f2bf(xs[(size_t)(2 * e) * 160000]);
            unsigned int hi = f2bf(xs[(size_t)(2 * e + 1) * 160000]);
            pk[e] = lo | (hi << 16);
        }
        uint4v* q = (uint4v*)xt + (size_t)g * 2;
        uint4v q0; q0[0] = pk[0]; q0[1] = pk[1]; q0[2] = pk[2]; q0[3] = pk[3];
        uint4v q1; q1[0] = pk[4]; q1[1] = pk[5]; q1[2] = pk[6]; q1[3] = pk[7];
        q[0] = q0; q[1] = q1;
    } else {
        const int s = (blk - 1250) * 256 + threadIdx.x;
        if (s < 41472) {
            const int ic = s / 2592, rem = s % 2592;
            const int oc = rem / 81, tap = rem % 81;
            wt[tap * 512 + oc * 16 + ic] = f2bf(w[s]);
        }
    }
}

// ---------- main conv: single-phase ----------
__global__ __launch_bounds__(256, 1) void conv4d_mfma(
    const ushort_t* __restrict__ xt, const ushort_t* __restrict__ wt,
    float* __restrict__ out)
{
    __shared__ ushort_t smem[57600];   // 9 slabs x 6400 ushorts = 115.2 KB
    __shared__ float edge[384];        // [wv][e1|e2a|e2b][ic8][r] = 4*3*2*16

    // bijective XCD swizzle: 648 blocks = 8 XCDs x 81 contiguous tiles
    const int wgid = blockIdx.x;
    const int tile_ = (wgid & 7) * 81 + (wgid >> 3);
    const int n = tile_ / 324;
    const int rem_ = tile_ - n * 324;
    const int j = rem_ / 18, i = rem_ % 18;

    const int t = threadIdx.x;
    const int lane = t & 63, wv = t >> 6;
    const int col = lane & 31, ic8 = lane >> 5;

    // slab-pos per tile m; reads at spc + c*20 (<= +40); clamp base to 359
    int sp[3]; int cb[3];
    #pragma unroll
    for (int m = 0; m < 3; ++m) {
        sp[m] = (3 * wv + m) * 32 + col;
        const int spc = sp[m] > 359 ? 359 : sp[m];
        cb[m] = spc * 32 + ic8 * 16;       // BYTES into a slab
    }

    f32x16 acc[3][3];   // [d][m]
    #pragma unroll
    for (int d = 0; d < 3; ++d)
        #pragma unroll
        for (int m = 0; m < 3; ++m)
            #pragma unroll
            for (int r = 0; r < 16; ++r) acc[d][m][r] = 0.0f;

    const ushort_t* xbase = xt + (size_t)n * 2560000;

    // ---- stage ALL 9 slabs; LDS dest = wave-uniform base (R7/R11 pattern) ----
    #pragma unroll
    for (int s9 = 0; s9 < 9; ++s9) {
        const int a = s9 / 3, b = s9 % 3;
        const ushort_t* g = xbase + (size_t)(i + a) * 128000 + (size_t)(j + b) * 6400;
        ushort_t* l = smem + s9 * 6400;
        ushort_t* l0 = l + (wv << 9);      // wave-uniform: wv*512 ushorts
        const ushort_t* gt = g + t * 8;    // per-lane global src
        gload16(gt,        l0);
        gload16(gt + 2048, l0 + 2048);
        gload16(gt + 4096, l0 + 4096);
        if (t < 32) gload16(g + 6144 + t * 8, l + 6144);
    }
    __syncthreads();   // the ONLY pre-epilogue barrier

    // ---- 81 uninterrupted compute steps ----
    #pragma unroll 3
    for (int ab = 0; ab < 9; ++ab) {
        const ushort_t* wtb = wt + (size_t)ab * 4608 + col * 16 + ic8 * 8;
        const char* lbase = (const char*)(smem + ab * 6400);
        #pragma unroll
        for (int c = 0; c < 3; ++c) {
            bf16x8 af0 = *(const bf16x8*)(wtb + (c * 3 + 0) * 512);
            bf16x8 af1 = *(const bf16x8*)(wtb + (c * 3 + 1) * 512);
            bf16x8 af2 = *(const bf16x8*)(wtb + (c * 3 + 2) * 512);
            #pragma unroll
            for (int m = 0; m < 3; ++m) {
                bf16x8 bv = *(const bf16x8*)(lbase + cb[m] + c * 640);
                acc[0][m] = __builtin_amdgcn_mfma_f32_32x32x16_bf16(af0, bv, acc[0][m], 0, 0, 0);
                acc[1][m] = __builtin_amdgcn_mfma_f32_32x32x16_bf16(af1, bv, acc[1][m], 0, 0, 0);
                acc[2][m] = __builtin_amdgcn_mfma_f32_32x32x16_bf16(af2, bv, acc[2][m], 0, 0, 0);
            }
        }
    }

    // ---- epilogue: out(k,l) = acc0[s] + acc1[s+1] + acc2[s+2], s=k*20+l ----
    if (col == 0) {
        #pragma unroll
        for (int r = 0; r < 16; ++r) {
            edge[((wv * 3 + 0) * 2 + ic8) * 16 + r] = acc[1][0][r];
            edge[((wv * 3 + 1) * 2 + ic8) * 16 + r] = acc[2][0][r];
        }
    } else if (col == 1) {
        #pragma unroll
        for (int r = 0; r < 16; ++r)
            edge[((wv * 3 + 2) * 2 + ic8) * 16 + r] = acc[2][0][r];
    }
    __syncthreads();
    const int nw = wv < 3 ? wv + 1 : 3;   // wave3's import is never consumed

    bool valm[3]; float* po[3];
    float* outn = out + (size_t)n * 3359232 + (size_t)i * 5832 + (size_t)j * 324
                      + (size_t)ic8 * 419904;
    #pragma unroll
    for (int m = 0; m < 3; ++m) {
        const int s = sp[m];
        const int k = s / 20, ls = s % 20;
        valm[m] = (ls <= 17) && (s <= 357);
        po[m] = outn + k * 18 + ls;
    }
    const int src1 = (lane & 32) | ((col + 1) & 31);
    const int src2 = (lane & 32) | ((col + 2) & 31);

    #pragma unroll
    for (int r = 0; r < 16; ++r) {
        const float e1  = edge[((nw * 3 + 0) * 2 + ic8) * 16 + r];
        const float e2a = edge[((nw * 3 + 1) * 2 + ic8) * 16 + r];
        const float e2b = edge[((nw * 3 + 2) * 2 + ic8) * 16 + r];
        float t1[4], t2[4];
        #pragma unroll
        for (int m = 0; m < 3; ++m) {
            t1[m] = __shfl(acc[1][m][r], src1, 64);
            t2[m] = __shfl(acc[2][m][r], src2, 64);
        }
        t1[3] = e1;
        t2[3] = (col == 30) ? e2a : e2b;
        const int offr = ((r & 3) + 8 * (r >> 2)) * 104976;
        #pragma unroll
        for (int m = 0; m < 3; ++m) {
            const float v1m = (col == 31) ? t1[m + 1] : t1[m];
            const float v2m = (col >= 30) ? t2[m + 1] : t2[m];
            const float res = acc[0][m][r] + v1m + v2m;
            if (valm[m]) po[m][offr] = res;
        }
    }
}

extern "C" void kernel_launch(void* const* d_in, const int* in_sizes, int n_in,
                              void* d_out, int out_size, void* d_ws, size_t ws_size,
                              hipStream_t stream) {
    const float* x = (const float*)d_in[0];
    const float* w = (const float*)d_in[1];
    float* out = (float*)d_out;

    ushort_t* xt = (ushort_t*)d_ws;                              // 10.24 MB
    ushort_t* wt = (ushort_t*)((char*)d_ws + (size_t)10240000);  // 83 KB

    prepass<<<dim3(1412), 256, 0, stream>>>(x, w, xt, wt);
    conv4d_mfma<<<dim3(648), 256, 0, stream>>>(xt, wt, out);
}

// Round 14
// 49.664 us; speedup vs baseline: 1.1520x; 1.1520x over previous
//
#include <hip/hip_runtime.h>

// Conv4d via implicit GEMM on MFMA (bf16 in, fp32 accum), DIRECT-GLOBAL.
// x (2,16,20^4) f32, w (16,32,3^4) f32 -> out (2,32,18^4) f32
//
// R14 vs R13: occupancy, for real this time. gfx950 unified reg pool is
// ~512/SIMD: R9..R13 all had VGPR+AGPR > 256 -> 1 wave/SIMD -> ~160 VMEM
// loads/wave with zero TLP -> latency convoy (R13: 13us/block for 2us of
// work, with ZERO barriers -- staging/barrier structure was never the wall).
// Fix: delete LDS staging entirely. B-fragments read DIRECT from xt global:
// 64 lanes x 16B contiguous = one coalesced 1KB wave-load, L2/L3-resident
// (R13: FETCH 7MB for 74MB slab reads). Removes ~60 VGPR of staging state
// -> ~90 VGPR + 144 AGPR <= 256 -> 2 waves/SIMD, 8 waves/CU, no barriers.
// Keeps (verified R13): d-shift inner loop (1 bv -> 3 MFMA), XCD swizzle,
// shfl+edgebuf epilogue, xt/wt prepass.

typedef unsigned short ushort_t;
typedef __attribute__((ext_vector_type(8)))  __bf16 bf16x8;
typedef __attribute__((ext_vector_type(16))) float  f32x16;
typedef __attribute__((ext_vector_type(4)))  unsigned int uint4v;

__device__ __forceinline__ ushort_t f2bf(float f) {
    union { float f; unsigned int u; } v; v.f = f;
    unsigned int r = v.u + 0x7FFFu + ((v.u >> 16) & 1u);   // RNE
    return (ushort_t)(r >> 16);
}

// ---------- fused prepass (verified R5-R13) ----------
// blocks 0..1249: x (NCHW f32) -> xt (N,spatial,ic bf16)
// blocks 1250..1411: w (ic,oc,tap f32) -> wt [tap][oc][ic] bf16
__global__ __launch_bounds__(256) void prepass(const float* __restrict__ x,
                                               const float* __restrict__ w,
                                               ushort_t* __restrict__ xt,
                                               ushort_t* __restrict__ wt) {
    const int blk = blockIdx.x;
    if (blk < 1250) {
        const int g = blk * 256 + threadIdx.x;          // 0..319999
        const int n = g / 160000, rem = g % 160000;
        const float* xs = x + (size_t)n * 2560000 + rem;
        unsigned int pk[8];
        #pragma unroll
        for (int e = 0; e < 8; ++e) {
            unsigned int lo = f2bf(xs[(size_t)(2 * e) * 160000]);
            unsigned int hi = f2bf(xs[(size_t)(2 * e + 1) * 160000]);
            pk[e] = lo | (hi << 16);
        }
        uint4v* q = (uint4v*)xt + (size_t)g * 2;
        uint4v q0; q0[0] = pk[0]; q0[1] = pk[1]; q0[2] = pk[2]; q0[3] = pk[3];
        uint4v q1; q1[0] = pk[4]; q1[1] = pk[5]; q1[2] = pk[6]; q1[3] = pk[7];
        q[0] = q0; q[1] = q1;
    } else {
        const int s = (blk - 1250) * 256 + threadIdx.x;
        if (s < 41472) {
            const int ic = s / 2592, rem = s % 2592;
            const int oc = rem / 81, tap = rem % 81;
            wt[tap * 512 + oc * 16 + ic] = f2bf(w[s]);
        }
    }
}

// ---------- main conv: direct-global, zero staging ----------
__global__ __launch_bounds__(256, 2) void conv4d_mfma(
    const ushort_t* __restrict__ xt, const ushort_t* __restrict__ wt,
    float* __restrict__ out)
{
    __shared__ float edge[384];        // [wv][e1|e2a|e2b][ic8][r] = 4*3*2*16

    // bijective XCD swizzle: 648 blocks = 8 XCDs x 81 contiguous tiles
    const int wgid = blockIdx.x;
    const int tile_ = (wgid & 7) * 81 + (wgid >> 3);
    const int n = tile_ / 324;
    const int rem_ = tile_ - n * 324;
    const int j = rem_ / 18, i = rem_ % 18;

    const int t = threadIdx.x;
    const int lane = t & 63, wv = t >> 6;
    const int col = lane & 31, ic8 = lane >> 5;

    // slab-pos per tile m; reads at spc + c*20 (<= +40); clamp base to 359
    int sp[3]; int cb[3];
    #pragma unroll
    for (int m = 0; m < 3; ++m) {
        sp[m] = (3 * wv + m) * 32 + col;
        const int spc = sp[m] > 359 ? 359 : sp[m];
        cb[m] = spc * 32 + ic8 * 16;       // BYTES into a slab
    }

    f32x16 acc[3][3];   // [d][m]
    #pragma unroll
    for (int d = 0; d < 3; ++d)
        #pragma unroll
        for (int m = 0; m < 3; ++m)
            #pragma unroll
            for (int r = 0; r < 16; ++r) acc[d][m][r] = 0.0f;

    const char* xnij = (const char*)(xt + (size_t)n * 2560000
                                        + (size_t)i * 128000 + (size_t)j * 6400);

    // ---- 81 compute steps, zero barriers, zero staging ----
    #pragma unroll 3
    for (int ab = 0; ab < 9; ++ab) {
        const int a = ab / 3, b = ab % 3;
        const char* xs = xnij + ((size_t)a * 128000 + (size_t)b * 6400) * 2;  // bytes
        const ushort_t* wtb = wt + (size_t)ab * 4608 + col * 16 + ic8 * 8;
        #pragma unroll
        for (int c = 0; c < 3; ++c) {
            bf16x8 af0 = *(const bf16x8*)(wtb + (c * 3 + 0) * 512);
            bf16x8 af1 = *(const bf16x8*)(wtb + (c * 3 + 1) * 512);
            bf16x8 af2 = *(const bf16x8*)(wtb + (c * 3 + 2) * 512);
            #pragma unroll
            for (int m = 0; m < 3; ++m) {
                bf16x8 bv = *(const bf16x8*)(xs + cb[m] + c * 640);
                acc[0][m] = __builtin_amdgcn_mfma_f32_32x32x16_bf16(af0, bv, acc[0][m], 0, 0, 0);
                acc[1][m] = __builtin_amdgcn_mfma_f32_32x32x16_bf16(af1, bv, acc[1][m], 0, 0, 0);
                acc[2][m] = __builtin_amdgcn_mfma_f32_32x32x16_bf16(af2, bv, acc[2][m], 0, 0, 0);
            }
        }
    }

    // ---- epilogue: out(k,l) = acc0[s] + acc1[s+1] + acc2[s+2], s=k*20+l ----
    if (col == 0) {
        #pragma unroll
        for (int r = 0; r < 16; ++r) {
            edge[((wv * 3 + 0) * 2 + ic8) * 16 + r] = acc[1][0][r];
            edge[((wv * 3 + 1) * 2 + ic8) * 16 + r] = acc[2][0][r];
        }
    } else if (col == 1) {
        #pragma unroll
        for (int r = 0; r < 16; ++r)
            edge[((wv * 3 + 2) * 2 + ic8) * 16 + r] = acc[2][0][r];
    }
    __syncthreads();
    const int nw = wv < 3 ? wv + 1 : 3;   // wave3's import is never consumed

    bool valm[3]; float* po[3];
    float* outn = out + (size_t)n * 3359232 + (size_t)i * 5832 + (size_t)j * 324
                      + (size_t)ic8 * 419904;
    #pragma unroll
    for (int m = 0; m < 3; ++m) {
        const int s = sp[m];
        const int k = s / 20, ls = s % 20;
        valm[m] = (ls <= 17) && (s <= 357);
        po[m] = outn + k * 18 + ls;
    }
    const int src1 = (lane & 32) | ((col + 1) & 31);
    const int src2 = (lane & 32) | ((col + 2) & 31);

    #pragma unroll
    for (int r = 0; r < 16; ++r) {
        const float e1  = edge[((nw * 3 + 0) * 2 + ic8) * 16 + r];
        const float e2a = edge[((nw * 3 + 1) * 2 + ic8) * 16 + r];
        const float e2b = edge[((nw * 3 + 2) * 2 + ic8) * 16 + r];
        float t1[4], t2[4];
        #pragma unroll
        for (int m = 0; m < 3; ++m) {
            t1[m] = __shfl(acc[1][m][r], src1, 64);
            t2[m] = __shfl(acc[2][m][r], src2, 64);
        }
        t1[3] = e1;
        t2[3] = (col == 30) ? e2a : e2b;
        const int offr = ((r & 3) + 8 * (r >> 2)) * 104976;
        #pragma unroll
        for (int m = 0; m < 3; ++m) {
            const float v1m = (col == 31) ? t1[m + 1] : t1[m];
            const float v2m = (col >= 30) ? t2[m + 1] : t2[m];
            const float res = acc[0][m][r] + v1m + v2m;
            if (valm[m]) po[m][offr] = res;
        }
    }
}

extern "C" void kernel_launch(void* const* d_in, const int* in_sizes, int n_in,
                              void* d_out, int out_size, void* d_ws, size_t ws_size,
                              hipStream_t stream) {
    const float* x = (const float*)d_in[0];
    const float* w = (const float*)d_in[1];
    float* out = (float*)d_out;

    ushort_t* xt = (ushort_t*)d_ws;                              // 10.24 MB
    ushort_t* wt = (ushort_t*)((char*)d_ws + (size_t)10240000);  // 83 KB

    prepass<<<dim3(1412), 256, 0, stream>>>(x, w, xt, wt);
    conv4d_mfma<<<dim3(648), 256, 0, stream>>>(xt, wt, out);
}

// Round 15
// 46.448 us; speedup vs baseline: 1.2318x; 1.0692x over previous
//
#include <hip/hip_runtime.h>

// Conv4d via implicit GEMM on MFMA (bf16 in, fp32 accum), 1-TILE-PER-WAVE.
// x (2,16,20^4) f32, w (16,32,3^4) f32 -> out (2,32,18^4) f32
//
// R15 vs R14: TLP. R14 proved legal 2-waves/SIMD barely moved the needle
// (occupancy 11.6%, conv 40.7us, all pipes <18%) -> exposed L2 latency with
// ~100 load-gaps/wave is the wall; only more waves/SIMD can hide it. The
// 144-AGPR acc[3][3] was the blocker. Fix: 1 tile/wave (acc[3]=48 AGPR),
// tiles OVERLAP by 2 (stride 30): wave T covers slab pos 30T..30T+31, emits
// cols 0..29, so out(s)=acc0[col]+acc1[col+1]+acc2[col+2] is pure in-wave
// shfl -- edgebuf + cross-wave epilogue deleted. 12 tiles x 30 = 360 pos.
// Grid 648x3=1944 blocks (block = 4 waves = 4 consecutive tiles), target
// 4 waves/SIMD (launch_bounds(256,4)), 16 waves/CU.
// Keeps: d-shift (1 bv -> 3 MFMA), direct-global B reads (R14), XCD swizzle,
// xt/wt prepass (R5-R14), clamp-to-359 (clamped lanes feed only invalid s).

typedef unsigned short ushort_t;
typedef __attribute__((ext_vector_type(8)))  __bf16 bf16x8;
typedef __attribute__((ext_vector_type(16))) float  f32x16;
typedef __attribute__((ext_vector_type(4)))  unsigned int uint4v;

__device__ __forceinline__ ushort_t f2bf(float f) {
    union { float f; unsigned int u; } v; v.f = f;
    unsigned int r = v.u + 0x7FFFu + ((v.u >> 16) & 1u);   // RNE
    return (ushort_t)(r >> 16);
}

// ---------- fused prepass (verified R5-R14) ----------
// blocks 0..1249: x (NCHW f32) -> xt (N,spatial,ic bf16)
// blocks 1250..1411: w (ic,oc,tap f32) -> wt [tap][oc][ic] bf16
__global__ __launch_bounds__(256) void prepass(const float* __restrict__ x,
                                               const float* __restrict__ w,
                                               ushort_t* __restrict__ xt,
                                               ushort_t* __restrict__ wt) {
    const int blk = blockIdx.x;
    if (blk < 1250) {
        const int g = blk * 256 + threadIdx.x;          // 0..319999
        const int n = g / 160000, rem = g % 160000;
        const float* xs = x + (size_t)n * 2560000 + rem;
        unsigned int pk[8];
        #pragma unroll
        for (int e = 0; e < 8; ++e) {
            unsigned int lo = f2bf(xs[(size_t)(2 * e) * 160000]);
            unsigned int hi = f2bf(xs[(size_t)(2 * e + 1) * 160000]);
            pk[e] = lo | (hi << 16);
        }
        uint4v* q = (uint4v*)xt + (size_t)g * 2;
        uint4v q0; q0[0] = pk[0]; q0[1] = pk[1]; q0[2] = pk[2]; q0[3] = pk[3];
        uint4v q1; q1[0] = pk[4]; q1[1] = pk[5]; q1[2] = pk[6]; q1[3] = pk[7];
        q[0] = q0; q[1] = q1;
    } else {
        const int s = (blk - 1250) * 256 + threadIdx.x;
        if (s < 41472) {
            const int ic = s / 2592, rem = s % 2592;
            const int oc = rem / 81, tap = rem % 81;
            wt[tap * 512 + oc * 16 + ic] = f2bf(w[s]);
        }
    }
}

// ---------- main conv: 1 tile/wave, direct-global, zero barriers ----------
__global__ __launch_bounds__(256, 4) void conv4d_mfma(
    const ushort_t* __restrict__ xt, const ushort_t* __restrict__ wt,
    float* __restrict__ out)
{
    // bijective XCD swizzle: 1944 blocks = 8 XCDs x 243 contiguous
    const int wgid = blockIdx.x;
    const int g = (wgid & 7) * 243 + (wgid >> 3);
    const int n = g / 972;
    int rem = g - n * 972;
    const int j = rem / 54;  rem -= j * 54;
    const int i = rem / 3;
    const int q = rem - i * 3;                 // tile-quad 0..2

    const int t = threadIdx.x;
    const int lane = t & 63, wv = t >> 6;
    const int col = lane & 31, ic8 = lane >> 5;

    const int T = q * 4 + wv;                  // wave tile 0..11
    const int sp = T * 30 + col;               // slab position (stride-30 tiles)
    const int spc = sp > 359 ? 359 : sp;       // clamp: reads stay in slab;
    const int cb = spc * 32 + ic8 * 16;        //   clamped lanes feed only s>357

    f32x16 acc0, acc1, acc2;                   // [d] — 48 AGPR total
    #pragma unroll
    for (int r = 0; r < 16; ++r) { acc0[r] = 0.0f; acc1[r] = 0.0f; acc2[r] = 0.0f; }

    const char* xnij = (const char*)(xt + (size_t)n * 2560000
                                        + (size_t)i * 128000 + (size_t)j * 6400);

    // ---- 81 compute steps, zero barriers, zero staging ----
    #pragma unroll 3
    for (int ab = 0; ab < 9; ++ab) {
        const int a = ab / 3, b = ab % 3;
        const char* xs = xnij + ((size_t)a * 128000 + (size_t)b * 6400) * 2;
        const ushort_t* wtb = wt + (size_t)ab * 4608 + col * 16 + ic8 * 8;
        #pragma unroll
        for (int c = 0; c < 3; ++c) {
            bf16x8 af0 = *(const bf16x8*)(wtb + (c * 3 + 0) * 512);
            bf16x8 af1 = *(const bf16x8*)(wtb + (c * 3 + 1) * 512);
            bf16x8 af2 = *(const bf16x8*)(wtb + (c * 3 + 2) * 512);
            bf16x8 bv  = *(const bf16x8*)(xs + cb + c * 640);
            acc0 = __builtin_amdgcn_mfma_f32_32x32x16_bf16(af0, bv, acc0, 0, 0, 0);
            acc1 = __builtin_amdgcn_mfma_f32_32x32x16_bf16(af1, bv, acc1, 0, 0, 0);
            acc2 = __builtin_amdgcn_mfma_f32_32x32x16_bf16(af2, bv, acc2, 0, 0, 0);
        }
    }

    // ---- epilogue: out(s) = acc0[col] + acc1[col+1] + acc2[col+2], all in-wave
    const int s = sp;
    const int k = s / 20, ls = s % 20;
    const bool val = (col <= 29) && (ls <= 17) && (s <= 357);
    float* po = out + (size_t)n * 3359232 + (size_t)i * 5832 + (size_t)j * 324
                    + (size_t)ic8 * 419904 + k * 18 + ls;
    const int src1 = (lane & 32) | ((col + 1) & 31);   // wrap only for invalid lanes
    const int src2 = (lane & 32) | ((col + 2) & 31);

    #pragma unroll
    for (int r = 0; r < 16; ++r) {
        const float v1 = __shfl(acc1[r], src1, 64);
        const float v2 = __shfl(acc2[r], src2, 64);
        const float res = acc0[r] + v1 + v2;
        const int offr = ((r & 3) + 8 * (r >> 2)) * 104976;
        if (val) po[offr] = res;
    }
}

extern "C" void kernel_launch(void* const* d_in, const int* in_sizes, int n_in,
                              void* d_out, int out_size, void* d_ws, size_t ws_size,
                              hipStream_t stream) {
    const float* x = (const float*)d_in[0];
    const float* w = (const float*)d_in[1];
    float* out = (float*)d_out;

    ushort_t* xt = (ushort_t*)d_ws;                              // 10.24 MB
    ushort_t* wt = (ushort_t*)((char*)d_ws + (size_t)10240000);  // 83 KB

    prepass<<<dim3(1412), 256, 0, stream>>>(x, w, xt, wt);
    conv4d_mfma<<<dim3(1944), 256, 0, stream>>>(xt, wt, out);
}

// Round 16
// 40.839 us; speedup vs baseline: 1.4009x; 1.1373x over previous
//
#include <hip/hip_runtime.h>

// Conv4d via implicit GEMM on MFMA (bf16 in, fp32 accum).
// x (2,16,20^4) f32, w (16,32,3^4) f32 -> out (2,32,18^4) f32
//
// R16 = R15 (1 tile/wave, stride-30 overlap tiles, in-wave shfl epilogue,
// 48-AGPR acc, direct-global bv, XCD swizzle) + af through LDS:
// R13-R15 ledger: ~108 x 1KB wave-loads per 81 MFMAs = 840 MB through the
// vector-L1 (~64 B/cyc/CU) = ~21us floor -> the invariant 35-48us plateau.
// 75% of that is the SAME 83KB of weights re-read by every wave. Fix: per-ab
// 9.2KB wt tap-block double-buffered in LDS (R11's verified wave-uniform
// gload16 staging + [tap][ic8][oc][ic_lo] layout -> contiguous 1KB af sweeps,
// 2-way banks = free). Per-wave VMEM 108KB -> 29KB. Regs ~123 <= 128 ->
// launch_bounds(256,4): 4 waves/SIMD, 4 blocks/CU; 9 per-ab barriers overlap
// across blocks.

typedef unsigned short ushort_t;
typedef __attribute__((ext_vector_type(8)))  __bf16 bf16x8;
typedef __attribute__((ext_vector_type(16))) float  f32x16;
typedef __attribute__((ext_vector_type(4)))  unsigned int uint4v;

__device__ __forceinline__ ushort_t f2bf(float f) {
    union { float f; unsigned int u; } v; v.f = f;
    unsigned int r = v.u + 0x7FFFu + ((v.u >> 16) & 1u);   // RNE
    return (ushort_t)(r >> 16);
}

__device__ __forceinline__ void gload16(const ushort_t* g, ushort_t* l) {
    __builtin_amdgcn_global_load_lds(
        (const __attribute__((address_space(1))) unsigned int*)g,
        (__attribute__((address_space(3))) unsigned int*)l, 16, 0, 0);
}

// ---------- fused prepass ----------
// blocks 0..1249: x (NCHW f32) -> xt (N,spatial,ic bf16)   [verified R5-R15]
// blocks 1250..1411: w -> wt [tap][ic8][oc][ic_lo] bf16    [verified R11]
__global__ __launch_bounds__(256) void prepass(const float* __restrict__ x,
                                               const float* __restrict__ w,
                                               ushort_t* __restrict__ xt,
                                               ushort_t* __restrict__ wt) {
    const int blk = blockIdx.x;
    if (blk < 1250) {
        const int g = blk * 256 + threadIdx.x;          // 0..319999
        const int n = g / 160000, rem = g % 160000;
        const float* xs = x + (size_t)n * 2560000 + rem;
        unsigned int pk[8];
        #pragma unroll
        for (int e = 0; e < 8; ++e) {
            unsigned int lo = f2bf(xs[(size_t)(2 * e) * 160000]);
            unsigned int hi = f2bf(xs[(size_t)(2 * e + 1) * 160000]);
            pk[e] = lo | (hi << 16);
        }
        uint4v* q = (uint4v*)xt + (size_t)g * 2;
        uint4v q0; q0[0] = pk[0]; q0[1] = pk[1]; q0[2] = pk[2]; q0[3] = pk[3];
        uint4v q1; q1[0] = pk[4]; q1[1] = pk[5]; q1[2] = pk[6]; q1[3] = pk[7];
        q[0] = q0; q[1] = q1;
    } else {
        const int s = (blk - 1250) * 256 + threadIdx.x;
        if (s < 41472) {
            const int ic = s / 2592, rem = s % 2592;
            const int oc = rem / 81, tap = rem % 81;
            wt[tap * 512 + (ic >> 3) * 256 + oc * 8 + (ic & 7)] = f2bf(w[s]);
        }
    }
}

// ---------- main conv: 1 tile/wave, af via LDS, bv direct-global ----------
__global__ __launch_bounds__(256, 4) void conv4d_mfma(
    const ushort_t* __restrict__ xt, const ushort_t* __restrict__ wt,
    float* __restrict__ out)
{
    __shared__ ushort_t lwt[2][4608];   // double-buffered wt tap-block, 9.2KB each

    // bijective XCD swizzle: 1944 blocks = 8 XCDs x 243 contiguous
    const int wgid = blockIdx.x;
    const int g = (wgid & 7) * 243 + (wgid >> 3);
    const int n = g / 972;
    int rem = g - n * 972;
    const int j = rem / 54;  rem -= j * 54;
    const int i = rem / 3;
    const int q = rem - i * 3;                 // tile-quad 0..2

    const int t = threadIdx.x;
    const int lane = t & 63, wv = t >> 6;
    const int col = lane & 31, ic8 = lane >> 5;

    const int T = q * 4 + wv;                  // wave tile 0..11
    const int sp = T * 30 + col;               // slab position (stride-30 tiles)
    const int spc = sp > 359 ? 359 : sp;       // clamp: clamped lanes feed only s>357
    const int cb = spc * 32 + ic8 * 16;        // BYTES into a slab
    const int aoffB = ic8 * 512 + col * 16;    // BYTES into a 1024B tap block

    f32x16 acc0, acc1, acc2;                   // 48 AGPR
    #pragma unroll
    for (int r = 0; r < 16; ++r) { acc0[r] = 0.0f; acc1[r] = 0.0f; acc2[r] = 0.0f; }

    const char* xnij = (const char*)(xt + (size_t)n * 2560000
                                        + (size_t)i * 128000 + (size_t)j * 6400);

    // prologue: stage wt tap-block 0 (R11-verified wave-uniform pattern)
    {
        const ushort_t* gw = wt;
        gload16(gw + t * 8,        lwt[0] + (wv << 9));
        gload16(gw + 2048 + t * 8, lwt[0] + 2048 + (wv << 9));
        if (t < 64) gload16(gw + 4096 + t * 8, lwt[0] + 4096);
    }

    for (int ab = 0; ab < 9; ++ab) {
        __syncthreads();   // lwt[ab&1] staged (barrier drains vmcnt); prev reads done

        if (ab < 8) {      // prefetch next tap-block, lands by next barrier
            const ushort_t* gw = wt + (size_t)(ab + 1) * 4608;
            ushort_t* lw = lwt[(ab + 1) & 1];
            gload16(gw + t * 8,        lw + (wv << 9));
            gload16(gw + 2048 + t * 8, lw + 2048 + (wv << 9));
            if (t < 64) gload16(gw + 4096 + t * 8, lw + 4096);
        }

        const int a = ab / 3, b = ab % 3;
        const char* xs = xnij + ((size_t)a * 128000 + (size_t)b * 6400) * 2;
        const char* wbase = (const char*)lwt[ab & 1];
        #pragma unroll
        for (int c = 0; c < 3; ++c) {
            bf16x8 af0 = *(const bf16x8*)(wbase + (c * 3 + 0) * 1024 + aoffB);
            bf16x8 af1 = *(const bf16x8*)(wbase + (c * 3 + 1) * 1024 + aoffB);
            bf16x8 af2 = *(const bf16x8*)(wbase + (c * 3 + 2) * 1024 + aoffB);
            bf16x8 bv  = *(const bf16x8*)(xs + cb + c * 640);
            acc0 = __builtin_amdgcn_mfma_f32_32x32x16_bf16(af0, bv, acc0, 0, 0, 0);
            acc1 = __builtin_amdgcn_mfma_f32_32x32x16_bf16(af1, bv, acc1, 0, 0, 0);
            acc2 = __builtin_amdgcn_mfma_f32_32x32x16_bf16(af2, bv, acc2, 0, 0, 0);
        }
    }

    // ---- epilogue: out(s) = acc0[col] + acc1[col+1] + acc2[col+2], in-wave ----
    const int s = sp;
    const int k = s / 20, ls = s % 20;
    const bool val = (col <= 29) && (ls <= 17) && (s <= 357);
    float* po = out + (size_t)n * 3359232 + (size_t)i * 5832 + (size_t)j * 324
                    + (size_t)ic8 * 419904 + k * 18 + ls;
    const int src1 = (lane & 32) | ((col + 1) & 31);
    const int src2 = (lane & 32) | ((col + 2) & 31);

    #pragma unroll
    for (int r = 0; r < 16; ++r) {
        const float v1 = __shfl(acc1[r], src1, 64);
        const float v2 = __shfl(acc2[r], src2, 64);
        const float res = acc0[r] + v1 + v2;
        const int offr = ((r & 3) + 8 * (r >> 2)) * 104976;
        if (val) po[offr] = res;
    }
}

extern "C" void kernel_launch(void* const* d_in, const int* in_sizes, int n_in,
                              void* d_out, int out_size, void* d_ws, size_t ws_size,
                              hipStream_t stream) {
    const float* x = (const float*)d_in[0];
    const float* w = (const float*)d_in[1];
    float* out = (float*)d_out;

    ushort_t* xt = (ushort_t*)d_ws;                              // 10.24 MB
    ushort_t* wt = (ushort_t*)((char*)d_ws + (size_t)10240000);  // 83 KB

    prepass<<<dim3(1412), 256, 0, stream>>>(x, w, xt, wt);
    conv4d_mfma<<<dim3(1944), 256, 0, stream>>>(xt, wt, out);
}